// Round 6
// baseline (67.951 us; speedup 1.0000x reference)
//
#include <hip/hip_runtime.h>
#include <math.h>

// x [B=32, C=64, T=32, H=28, W=28] f32, layout idx = ((bc*T + t)*HW + hw).
// LIF recurrence over t (stride HW). Spikes (0/1 f32) out, same layout.
//
// R5: L3-partition experiment. R4 showed NT-stores let ~47% of x stay
// Infinity-Cache-resident across graph replays (FETCH 205->108.6 MB). To beat
// the replacement policy's thrash, split x explicitly:
//   bc < BC_TEMP  (75%, ~154 MB): temporal loads -> sized to stay resident
//   bc >= BC_TEMP (25%, ~51 MB):  nontemporal loads -> never pollutes L3
// NT stores for out (write-once) as in R4.
typedef float f4 __attribute__((ext_vector_type(4)));

#define TT   32
#define HW4  196            // 784/4 float4 per (bc,t) slice
#define BC   (32 * 64)      // 2048
#define BC_TEMP 1536        // temporal partition: 75% of x (~154 MB < L3)
#define NTHREADS (BC * HW4) // 401408 = 6272 * 64

__device__ __forceinline__ float spike_of(float u) {
    return u > 0.5f ? 1.0f : 0.0f;
}

// s_old ∈ {0,1} exactly, so the select form is bit-identical to the
// reference's (mem*d)*(1-s). __fmul_rn/__fadd_rn forbid FMA contraction so
// rounding matches a plain f32 mul-then-add chain.
template <bool NT_LOAD>
__device__ __forceinline__ void lif_run(const f4* __restrict__ x,
                                        f4* __restrict__ out,
                                        size_t base, float d) {
    f4 mem = NT_LOAD ? __builtin_nontemporal_load(x + base) : x[base];
    f4 s;
    s.x = spike_of(mem.x);
    s.y = spike_of(mem.y);
    s.z = spike_of(mem.z);
    s.w = spike_of(mem.w);
    __builtin_nontemporal_store(s, out + base);

    #pragma unroll
    for (int t = 1; t < TT; ++t) {
        const size_t idx = base + (size_t)t * HW4;
        const f4 xt = NT_LOAD ? __builtin_nontemporal_load(x + idx) : x[idx];
        mem.x = __fadd_rn(s.x != 0.0f ? 0.0f : __fmul_rn(mem.x, d), xt.x);
        mem.y = __fadd_rn(s.y != 0.0f ? 0.0f : __fmul_rn(mem.y, d), xt.y);
        mem.z = __fadd_rn(s.z != 0.0f ? 0.0f : __fmul_rn(mem.z, d), xt.z);
        mem.w = __fadd_rn(s.w != 0.0f ? 0.0f : __fmul_rn(mem.w, d), xt.w);
        s.x = spike_of(mem.x);
        s.y = spike_of(mem.y);
        s.z = spike_of(mem.z);
        s.w = spike_of(mem.w);
        __builtin_nontemporal_store(s, out + idx);
    }
}

__global__ __launch_bounds__(64) void lif_fwd_kernel(
        const f4* __restrict__ x,
        const float* __restrict__ decay,
        f4* __restrict__ out) {
    const int tid = blockIdx.x * 64 + threadIdx.x;   // grid exact
    const int bc  = tid / HW4;
    const int hw4 = tid - bc * HW4;
    const size_t base = (size_t)bc * (TT * HW4) + (size_t)hw4;

    // d = sigmoid(decay[0]); step-by-step f32 to match reference rounding.
    const float e = expf(-decay[0]);
    const float d = 1.0f / (1.0f + e);

    if (bc < BC_TEMP) {
        lif_run<false>(x, out, base, d);   // temporal: stays L3-resident
    } else {
        lif_run<true>(x, out, base, d);    // NT: streamed, no pollution
    }
}

extern "C" void kernel_launch(void* const* d_in, const int* in_sizes, int n_in,
                              void* d_out, int out_size, void* d_ws, size_t ws_size,
                              hipStream_t stream) {
    const f4*    x     = (const f4*)d_in[0];
    const float* decay = (const float*)d_in[1];
    f4*          out   = (f4*)d_out;

    const int block = 64;
    const int grid  = NTHREADS / block;  // 6272, exact
    lif_fwd_kernel<<<grid, block, 0, stream>>>(x, decay, out);
}

// Round 7
// 67.549 us; speedup vs baseline: 1.0060x; 1.0060x over previous
//
#include <hip/hip_runtime.h>
#include <math.h>

// x [B=32, C=64, T=32, H=28, W=28] f32, layout idx = ((bc*T + t)*HW + hw).
// LIF recurrence over t (stride HW). Spikes (0/1 f32) out, same layout.
//
// R6 = R4 (temporal loads for x -> ~47% stays Infinity-Cache-resident across
// graph replays; NT stores for write-once out) + block=128 for occupancy:
// block=64 capped at ~16 waves/CU (43.5% occ, WG-slot limit) and left HBM at
// 72% of the copy ceiling. 128 threads/WG -> 3136 WGs = 12.25 WG/CU, whole
// grid co-resident, ~24+ waves/CU.
typedef float f4 __attribute__((ext_vector_type(4)));

#define TT   32
#define HW4  196            // 784/4 float4 per (bc,t) slice
#define BC   (32 * 64)      // 2048
#define NTHREADS (BC * HW4) // 401408 = 3136 * 128

__device__ __forceinline__ float spike_of(float u) {
    return u > 0.5f ? 1.0f : 0.0f;
}

__global__ __launch_bounds__(128) void lif_fwd_kernel(
        const f4* __restrict__ x,
        const float* __restrict__ decay,
        f4* __restrict__ out) {
    const int tid = blockIdx.x * 128 + threadIdx.x;  // grid exact
    const int bc  = tid / HW4;
    const int hw4 = tid - bc * HW4;
    const size_t base = (size_t)bc * (TT * HW4) + (size_t)hw4;

    // d = sigmoid(decay[0]); step-by-step f32 to match reference rounding.
    const float e = expf(-decay[0]);
    const float d = 1.0f / (1.0f + e);

    // t = 0: mem = x0, spike = (mem > 0.5)
    f4 mem = x[base];            // temporal load: x allocates in L2/L3
    f4 s;
    s.x = spike_of(mem.x);
    s.y = spike_of(mem.y);
    s.z = spike_of(mem.z);
    s.w = spike_of(mem.w);
    __builtin_nontemporal_store(s, out + base);

    // t >= 1: mem = mem_old*d*(1-s_old) + x_t ; s = (mem > 0.5)
    // s_old ∈ {0,1} exactly, so the select form is bit-identical to the
    // reference's (mem*d)*(1-s). __fmul_rn/__fadd_rn forbid FMA contraction
    // so rounding matches a plain f32 mul-then-add chain.
    #pragma unroll
    for (int t = 1; t < TT; ++t) {
        const size_t idx = base + (size_t)t * HW4;
        const f4 xt = x[idx];
        mem.x = __fadd_rn(s.x != 0.0f ? 0.0f : __fmul_rn(mem.x, d), xt.x);
        mem.y = __fadd_rn(s.y != 0.0f ? 0.0f : __fmul_rn(mem.y, d), xt.y);
        mem.z = __fadd_rn(s.z != 0.0f ? 0.0f : __fmul_rn(mem.z, d), xt.z);
        mem.w = __fadd_rn(s.w != 0.0f ? 0.0f : __fmul_rn(mem.w, d), xt.w);
        s.x = spike_of(mem.x);
        s.y = spike_of(mem.y);
        s.z = spike_of(mem.z);
        s.w = spike_of(mem.w);
        __builtin_nontemporal_store(s, out + idx);
    }
}

extern "C" void kernel_launch(void* const* d_in, const int* in_sizes, int n_in,
                              void* d_out, int out_size, void* d_ws, size_t ws_size,
                              hipStream_t stream) {
    const f4*    x     = (const f4*)d_in[0];
    const float* decay = (const float*)d_in[1];
    f4*          out   = (f4*)d_out;

    const int block = 128;
    const int grid  = NTHREADS / block;  // 3136, exact
    lif_fwd_kernel<<<grid, block, 0, stream>>>(x, decay, out);
}